// Round 2
// baseline (532.965 us; speedup 1.0000x reference)
//
#include <hip/hip_runtime.h>
#include <hip/hip_bf16.h>

#define S_LEN 4096
#define DMODEL 512
#define NHEAD 8
#define HDIM 64

typedef __bf16 bf16x8 __attribute__((ext_vector_type(8)));
typedef float f32x4 __attribute__((ext_vector_type(4)));

// ---------------- projection (q/k): y[s][h][d] = sum_d' x[s][h][d'] W[d][d'] + b[d] ----------------
__global__ __launch_bounds__(256) void proj_kernel(const float* __restrict__ x,
                                                   const float* __restrict__ W,
                                                   const float* __restrict__ b,
                                                   __bf16* __restrict__ y) {
    __shared__ float Ws[64][65];
    int t = threadIdx.x;
    for (int i = t; i < 4096; i += 256) Ws[i >> 6][i & 63] = W[i];
    __syncthreads();
    int lane = t & 63;
    int gw = blockIdx.x * 4 + (t >> 6);          // gw = s*8 + h, 4 rows per block
    const float* xrow = x + (size_t)gw * 64;
    float xv = xrow[lane];
    float acc = b[lane];
#pragma unroll
    for (int i = 0; i < 64; ++i) acc += __shfl(xv, i) * Ws[lane][i];
    y[(size_t)gw * 64 + lane] = (__bf16)acc;
}

// ---------------- projection (v) with transpose: vt[h][d][s] ----------------
__global__ __launch_bounds__(256) void proj_v_kernel(const float* __restrict__ x,
                                                     const float* __restrict__ W,
                                                     const float* __restrict__ b,
                                                     __bf16* __restrict__ vt) {
    __shared__ float Ws[64][65];
    __shared__ float T[64][65];
    int h = blockIdx.x & 7, st = blockIdx.x >> 3;
    int s0 = st * 64;
    int t = threadIdx.x, lane = t & 63, w = t >> 6;
    for (int i = t; i < 4096; i += 256) Ws[i >> 6][i & 63] = W[i];
    __syncthreads();
    float bv = b[lane];
    for (int p = 0; p < 16; ++p) {
        int sl = w * 16 + p;
        float xv = x[((size_t)(s0 + sl) * 8 + h) * 64 + lane];
        float acc = bv;
#pragma unroll
        for (int i = 0; i < 64; ++i) acc += __shfl(xv, i) * Ws[lane][i];
        T[sl][lane] = acc;
    }
    __syncthreads();
    for (int p = 0; p < 16; ++p) {
        int d = p * 4 + w;
        vt[((size_t)h * 64 + d) * 4096 + s0 + lane] = (__bf16)T[lane][d];
    }
}

// ---------------- mask packing: pack[qi][w] bit ki = (mask[qi][ki] != 0) ----------------
__global__ __launch_bounds__(256) void maskpack_kernel(const int* __restrict__ mask,
                                                       unsigned int* __restrict__ pack) {
    int t = threadIdx.x, lane = t & 63;
    int gw = blockIdx.x * 4 + (t >> 6);          // wave id: qi*64 + seg
    int qi = gw >> 6, seg = gw & 63;
    int ki = seg * 64 + lane;
    unsigned long long bits = __ballot(mask[(size_t)qi * 4096 + ki] != 0);
    if (lane == 0) {
        pack[(size_t)qi * 128 + seg * 2]     = (unsigned int)bits;
        pack[(size_t)qi * 128 + seg * 2 + 1] = (unsigned int)(bits >> 32);
    }
}

// ---------------- f32 -> bf16 convert ----------------
__global__ __launch_bounds__(256) void cvt_kernel(const float* __restrict__ src,
                                                  __bf16* __restrict__ dst, int n) {
    int i = blockIdx.x * 256 + threadIdx.x;
    if (i < n) dst[i] = (__bf16)src[i];
}

// ---------------- flash attention (split-KV) ----------------
// block: h = bid&7, qt = (bid>>3)&63, split = bid>>9
// 4 waves, wave handles 16 q rows; KV step = 64; per-wave P tile (no barrier needed)
__global__ __launch_bounds__(256, 8) void attn_kernel(const __bf16* __restrict__ qb,
                                                      const __bf16* __restrict__ kb,
                                                      const __bf16* __restrict__ vt,
                                                      const unsigned int* __restrict__ mp,
                                                      int kv_len,
                                                      float* __restrict__ opart,
                                                      float* __restrict__ stats,
                                                      __bf16* __restrict__ ao) {
    int bid = blockIdx.x;
    int h = bid & 7, qt = (bid >> 3) & 63, sp = bid >> 9;
    int kv0 = sp * kv_len;
    int t = threadIdx.x, wave = t >> 6, lane = t & 63, lg = lane >> 4, lc = lane & 15;
    int q0 = qt * 64 + wave * 16;

    __shared__ __bf16 P[2][4][16 * 64];   // double-buffered, per-wave 16x64 tile, XOR-swizzled

    // Q fragments (A-layout: row = lane&15, k = (lane>>4)*8 + j)
    const __bf16* qrow = qb + ((size_t)(q0 + lc) * 8 + h) * 64 + lg * 8;
    bf16x8 qf0 = *(const bf16x8*)(qrow);
    bf16x8 qf1 = *(const bf16x8*)(qrow + 32);

    f32x4 o0 = {0,0,0,0}, o1 = {0,0,0,0}, o2 = {0,0,0,0}, o3 = {0,0,0,0};
    float m_[4] = {-3e38f, -3e38f, -3e38f, -3e38f};
    float l_[4] = {0.f, 0.f, 0.f, 0.f};

    const unsigned int* mprow[4];
#pragma unroll
    for (int r = 0; r < 4; ++r) mprow[r] = mp + (size_t)(q0 + lg * 4 + r) * 128;

    const __bf16* vbase = vt + (size_t)h * 64 * 4096;

    for (int kb_i = kv0; kb_i < kv0 + kv_len; kb_i += 64) {
        int buf = (kb_i >> 6) & 1;
        // ---- QK^T: 4 tiles of 16q x 16k ----
        f32x4 sc[4];
#pragma unroll
        for (int kc = 0; kc < 4; ++kc) {
            const __bf16* kr = kb + ((size_t)(kb_i + kc * 16 + lc) * 8 + h) * 64 + lg * 8;
            bf16x8 kf0 = *(const bf16x8*)(kr);
            bf16x8 kf1 = *(const bf16x8*)(kr + 32);
            f32x4 z = {0,0,0,0};
            z = __builtin_amdgcn_mfma_f32_16x16x32_bf16(qf0, kf0, z, 0, 0, 0);
            z = __builtin_amdgcn_mfma_f32_16x16x32_bf16(qf1, kf1, z, 0, 0, 0);
            sc[kc] = z;
        }
        // ---- mask (before scale) + online softmax ----
        float pv[4][4];   // [kc][r]
        float tmax[4];
#pragma unroll
        for (int r = 0; r < 4; ++r) {
            unsigned int w0 = mprow[r][(kb_i >> 5)];
            unsigned int w1 = mprow[r][(kb_i >> 5) + 1];
            float vmax = -3e38f;
#pragma unroll
            for (int kc = 0; kc < 4; ++kc) {
                unsigned int wsel = (kc < 2) ? w0 : w1;
                int bitpos = (kc & 1) * 16 + lc;
                float val = ((wsel >> bitpos) & 1u) ? sc[kc][r] * 0.125f : -1.25e19f;
                pv[kc][r] = val;
                vmax = fmaxf(vmax, val);
            }
            tmax[r] = vmax;
        }
#pragma unroll
        for (int r = 0; r < 4; ++r) {
            float v = tmax[r];
            v = fmaxf(v, __shfl_xor(v, 1));
            v = fmaxf(v, __shfl_xor(v, 2));
            v = fmaxf(v, __shfl_xor(v, 4));
            v = fmaxf(v, __shfl_xor(v, 8));
            float mn = fmaxf(m_[r], v);
            float corr = __expf(m_[r] - mn);
            m_[r] = mn;
            float ps = 0.f;
#pragma unroll
            for (int kc = 0; kc < 4; ++kc) {
                float p = __expf(pv[kc][r] - mn);
                pv[kc][r] = p;
                ps += p;
            }
            ps += __shfl_xor(ps, 1);
            ps += __shfl_xor(ps, 2);
            ps += __shfl_xor(ps, 4);
            ps += __shfl_xor(ps, 8);
            l_[r] = l_[r] * corr + ps;
            o0[r] *= corr; o1[r] *= corr; o2[r] *= corr; o3[r] *= corr;
        }
        // ---- write P (bf16) to per-wave swizzled LDS tile (no cross-wave sharing -> no barrier) ----
        char* pbase = (char*)&P[buf][wave][0];
#pragma unroll
        for (int kc = 0; kc < 4; ++kc)
#pragma unroll
            for (int r = 0; r < 4; ++r) {
                int row = lg * 4 + r, col = kc * 16 + lc;
                int byte = ((row * 64 + col) * 2) ^ ((row & 7) << 4);
                *(__bf16*)(pbase + byte) = (__bf16)pv[kc][r];
            }
        // ---- PV: O += P * V ----
#pragma unroll
        for (int kk = 0; kk < 2; ++kk) {
            int byte = ((lc * 64 + kk * 32 + lg * 8) * 2) ^ ((lc & 7) << 4);
            bf16x8 pf = *(const bf16x8*)((const char*)&P[buf][wave][0] + byte);
            const __bf16* vb = vbase + kb_i + kk * 32 + lg * 8;
            o0 = __builtin_amdgcn_mfma_f32_16x16x32_bf16(pf, *(const bf16x8*)(vb + (size_t)(0 * 16 + lc) * 4096), o0, 0, 0, 0);
            o1 = __builtin_amdgcn_mfma_f32_16x16x32_bf16(pf, *(const bf16x8*)(vb + (size_t)(1 * 16 + lc) * 4096), o1, 0, 0, 0);
            o2 = __builtin_amdgcn_mfma_f32_16x16x32_bf16(pf, *(const bf16x8*)(vb + (size_t)(2 * 16 + lc) * 4096), o2, 0, 0, 0);
            o3 = __builtin_amdgcn_mfma_f32_16x16x32_bf16(pf, *(const bf16x8*)(vb + (size_t)(3 * 16 + lc) * 4096), o3, 0, 0, 0);
        }
    }
    if (opart) {
        // ---- partial epilogue: unnormalized fp32 O + (m,l) stats ----
#pragma unroll
        for (int r = 0; r < 4; ++r) {
            int row = q0 + lg * 4 + r;
            size_t rh = ((size_t)sp * 4096 + row) * 8 + h;
            float* dst = opart + rh * 64;
            dst[0 * 16 + lc] = o0[r];
            dst[1 * 16 + lc] = o1[r];
            dst[2 * 16 + lc] = o2[r];
            dst[3 * 16 + lc] = o3[r];
            if (lc == 0) {
                stats[rh * 2]     = m_[r];
                stats[rh * 2 + 1] = l_[r];
            }
        }
    } else {
        // ---- final epilogue: normalize, write bf16 [s][h*64+d] ----
#pragma unroll
        for (int r = 0; r < 4; ++r) {
            float inv = 1.0f / l_[r];
            int row = q0 + lg * 4 + r;
            __bf16* dst = ao + (size_t)row * 512 + h * 64;
            dst[0 * 16 + lc] = (__bf16)(o0[r] * inv);
            dst[1 * 16 + lc] = (__bf16)(o1[r] * inv);
            dst[2 * 16 + lc] = (__bf16)(o2[r] * inv);
            dst[3 * 16 + lc] = (__bf16)(o3[r] * inv);
        }
    }
}

// ---------------- split-KV combine: merge nsplit partials into bf16 ao ----------------
__global__ __launch_bounds__(256) void combine_kernel(const float* __restrict__ opart,
                                                      const float* __restrict__ stats,
                                                      __bf16* __restrict__ ao, int nsplit) {
    int t = threadIdx.x, lane = t & 63, w = t >> 6;
    int rh = blockIdx.x * 4 + w;     // row*8 + h
    float m_i[4], l_i[4];
    float M = -3e38f;
#pragma unroll 4
    for (int sp = 0; sp < nsplit; ++sp) {
        m_i[sp] = stats[((size_t)sp * 32768 + rh) * 2];
        l_i[sp] = stats[((size_t)sp * 32768 + rh) * 2 + 1];
        M = fmaxf(M, m_i[sp]);
    }
    float L = 0.f, acc = 0.f;
#pragma unroll 4
    for (int sp = 0; sp < nsplit; ++sp) {
        float scl = __expf(m_i[sp] - M);
        L += l_i[sp] * scl;
        acc += opart[((size_t)sp * 32768 + rh) * 64 + lane] * scl;
    }
    int row = rh >> 3, h = rh & 7;
    ao[(size_t)row * 512 + h * 64 + lane] = (__bf16)(acc / L);
}

// ---------------- final FC: out[s][n] = sum_k ao[s][k] * Wfc[n][k] + bfc[n] ----------------
__global__ __launch_bounds__(256) void fc_kernel(const __bf16* __restrict__ ao,
                                                 const __bf16* __restrict__ Wb,
                                                 const float* __restrict__ bfc,
                                                 float* __restrict__ out) {
    int bid = blockIdx.x;
    int stile = bid >> 3, nt = bid & 7;
    int t = threadIdx.x, wave = t >> 6, lane = t & 63, lg = lane >> 4, lc = lane & 15;
    int s0 = stile * 64 + wave * 16;
    int n0 = nt * 64;
    f32x4 c0 = {0,0,0,0}, c1 = {0,0,0,0}, c2 = {0,0,0,0}, c3 = {0,0,0,0};
    for (int k0 = 0; k0 < 512; k0 += 32) {
        bf16x8 af = *(const bf16x8*)(ao + (size_t)(s0 + lc) * 512 + k0 + lg * 8);
        const __bf16* wb = Wb + k0 + lg * 8;
        c0 = __builtin_amdgcn_mfma_f32_16x16x32_bf16(af, *(const bf16x8*)(wb + (size_t)(n0 + 0 * 16 + lc) * 512), c0, 0, 0, 0);
        c1 = __builtin_amdgcn_mfma_f32_16x16x32_bf16(af, *(const bf16x8*)(wb + (size_t)(n0 + 1 * 16 + lc) * 512), c1, 0, 0, 0);
        c2 = __builtin_amdgcn_mfma_f32_16x16x32_bf16(af, *(const bf16x8*)(wb + (size_t)(n0 + 2 * 16 + lc) * 512), c2, 0, 0, 0);
        c3 = __builtin_amdgcn_mfma_f32_16x16x32_bf16(af, *(const bf16x8*)(wb + (size_t)(n0 + 3 * 16 + lc) * 512), c3, 0, 0, 0);
    }
#pragma unroll
    for (int r = 0; r < 4; ++r) {
        int row = s0 + lg * 4 + r;
        float* dst = out + (size_t)row * 512 + n0;
        dst[0 * 16 + lc] = c0[r] + bfc[n0 + 0 * 16 + lc];
        dst[1 * 16 + lc] = c1[r] + bfc[n0 + 1 * 16 + lc];
        dst[2 * 16 + lc] = c2[r] + bfc[n0 + 2 * 16 + lc];
        dst[3 * 16 + lc] = c3[r] + bfc[n0 + 3 * 16 + lc];
    }
}

extern "C" void kernel_launch(void* const* d_in, const int* in_sizes, int n_in,
                              void* d_out, int out_size, void* d_ws, size_t ws_size,
                              hipStream_t stream) {
    const float* query = (const float*)d_in[0];
    const float* key   = (const float*)d_in[1];
    const float* value = (const float*)d_in[2];
    const int*   mask  = (const int*)d_in[3];
    const float* Wq  = (const float*)d_in[4];
    const float* bq  = (const float*)d_in[5];
    const float* Wk  = (const float*)d_in[6];
    const float* bk  = (const float*)d_in[7];
    const float* Wv  = (const float*)d_in[8];
    const float* bv  = (const float*)d_in[9];
    const float* Wfc = (const float*)d_in[10];
    const float* bfc = (const float*)d_in[11];

    char* ws = (char*)d_ws;
    const size_t MB = 1024 * 1024;
    __bf16* q_bf   = (__bf16*)(ws + 0 * MB);      // 4 MB  [S][H][64]
    __bf16* k_bf   = (__bf16*)(ws + 4 * MB);      // 4 MB  [S][H][64]
    __bf16* vt     = (__bf16*)(ws + 8 * MB);      // 4 MB  [H][64][S]
    __bf16* ao     = (__bf16*)(ws + 12 * MB);     // 4 MB  [S][512]
    __bf16* wfc_bf = (__bf16*)(ws + 16 * MB);     // 0.5 MB
    unsigned int* mpack = (unsigned int*)(ws + 17 * MB);  // 2 MB [S][128]
    const size_t base = 19 * MB;
    // split-KV partials: per split 8 MB fp32 O + 256 KB stats
    int nsplit = 1;
    if (ws_size >= base + 4 * (8 * MB + 262144)) nsplit = 4;
    else if (ws_size >= base + 2 * (8 * MB + 262144)) nsplit = 2;
    float* opart = (float*)(ws + base);
    float* stats = (float*)(ws + base + (size_t)nsplit * 8 * MB);

    proj_kernel<<<8192, 256, 0, stream>>>(query, Wq, bq, q_bf);
    proj_kernel<<<8192, 256, 0, stream>>>(key, Wk, bk, k_bf);
    proj_v_kernel<<<512, 256, 0, stream>>>(value, Wv, bv, vt);
    maskpack_kernel<<<65536, 256, 0, stream>>>(mask, mpack);
    cvt_kernel<<<1024, 256, 0, stream>>>(Wfc, wfc_bf, 262144);
    if (nsplit > 1) {
        attn_kernel<<<512 * nsplit, 256, 0, stream>>>(q_bf, k_bf, vt, mpack,
                                                      S_LEN / nsplit, opart, stats, ao);
        combine_kernel<<<8192, 256, 0, stream>>>(opart, stats, ao, nsplit);
    } else {
        attn_kernel<<<512, 256, 0, stream>>>(q_bf, k_bf, vt, mpack,
                                             S_LEN, nullptr, nullptr, ao);
    }
    fc_kernel<<<512, 256, 0, stream>>>(ao, wfc_bf, bfc, (float*)d_out);
}

// Round 3
// 309.315 us; speedup vs baseline: 1.7230x; 1.7230x over previous
//
#include <hip/hip_runtime.h>
#include <hip/hip_bf16.h>

#define S_LEN 4096
#define DMODEL 512
#define NHEAD 8
#define HDIM 64

typedef __bf16 bf16x8 __attribute__((ext_vector_type(8)));
typedef float f32x4 __attribute__((ext_vector_type(4)));

__device__ __forceinline__ void gload_lds16(const void* g, void* l) {
    __builtin_amdgcn_global_load_lds((const __attribute__((address_space(1))) void*)g,
                                     (__attribute__((address_space(3))) void*)l, 16, 0, 0);
}

// ---------------- projection (q/k): y[s][h][d] = sum_d' x[s][h][d'] W[d][d'] + b[d] ----------------
__global__ __launch_bounds__(256) void proj_kernel(const float* __restrict__ x,
                                                   const float* __restrict__ W,
                                                   const float* __restrict__ b,
                                                   __bf16* __restrict__ y) {
    __shared__ float Ws[64][65];
    int t = threadIdx.x;
    for (int i = t; i < 4096; i += 256) Ws[i >> 6][i & 63] = W[i];
    __syncthreads();
    int lane = t & 63;
    int gw = blockIdx.x * 4 + (t >> 6);          // gw = s*8 + h, 4 rows per block
    const float* xrow = x + (size_t)gw * 64;
    float xv = xrow[lane];
    float acc = b[lane];
#pragma unroll
    for (int i = 0; i < 64; ++i) acc += __shfl(xv, i) * Ws[lane][i];
    y[(size_t)gw * 64 + lane] = (__bf16)acc;
}

// ---------------- projection (v) with transpose: vt[h][d][s] ----------------
__global__ __launch_bounds__(256) void proj_v_kernel(const float* __restrict__ x,
                                                     const float* __restrict__ W,
                                                     const float* __restrict__ b,
                                                     __bf16* __restrict__ vt) {
    __shared__ float Ws[64][65];
    __shared__ float T[64][65];
    int h = blockIdx.x & 7, st = blockIdx.x >> 3;
    int s0 = st * 64;
    int t = threadIdx.x, lane = t & 63, w = t >> 6;
    for (int i = t; i < 4096; i += 256) Ws[i >> 6][i & 63] = W[i];
    __syncthreads();
    float bv = b[lane];
    for (int p = 0; p < 16; ++p) {
        int sl = w * 16 + p;
        float xv = x[((size_t)(s0 + sl) * 8 + h) * 64 + lane];
        float acc = bv;
#pragma unroll
        for (int i = 0; i < 64; ++i) acc += __shfl(xv, i) * Ws[lane][i];
        T[sl][lane] = acc;
    }
    __syncthreads();
    for (int p = 0; p < 16; ++p) {
        int d = p * 4 + w;
        vt[((size_t)h * 64 + d) * 4096 + s0 + lane] = (__bf16)T[lane][d];
    }
}

// ---------------- mask packing: pack[qi][w] bit ki = (mask[qi][ki] != 0) ----------------
__global__ __launch_bounds__(256) void maskpack_kernel(const int* __restrict__ mask,
                                                       unsigned int* __restrict__ pack) {
    int t = threadIdx.x, lane = t & 63;
    int gw = blockIdx.x * 4 + (t >> 6);          // wave id: qi*64 + seg
    int qi = gw >> 6, seg = gw & 63;
    int ki = seg * 64 + lane;
    unsigned long long bits = __ballot(mask[(size_t)qi * 4096 + ki] != 0);
    if (lane == 0) {
        pack[(size_t)qi * 128 + seg * 2]     = (unsigned int)bits;
        pack[(size_t)qi * 128 + seg * 2 + 1] = (unsigned int)(bits >> 32);
    }
}

// ---------------- f32 -> bf16 convert ----------------
__global__ __launch_bounds__(256) void cvt_kernel(const float* __restrict__ src,
                                                  __bf16* __restrict__ dst, int n) {
    int i = blockIdx.x * 256 + threadIdx.x;
    if (i < n) dst[i] = (__bf16)src[i];
}

// ---------------- flash attention (LDS-staged, double-buffered) ----------------
// block: h = bid&7 (head -> XCD for K/V L2 residency), qt = bid>>3
// 4 waves x 16 q-rows; KV step 64. K/V staged to LDS via global_load_lds (shared
// by all waves), XOR-swizzled (inverse swizzle on global source, rule 21).
__global__ __launch_bounds__(256, 2) void attn_kernel(const __bf16* __restrict__ qb,
                                                      const __bf16* __restrict__ kb,
                                                      const __bf16* __restrict__ vt,
                                                      const unsigned int* __restrict__ mp,
                                                      __bf16* __restrict__ ao) {
    int bid = blockIdx.x;
    int h = bid & 7, qt = bid >> 3;
    int t = threadIdx.x, wave = t >> 6, lane = t & 63, lg = lane >> 4, lc = lane & 15;
    int q0 = qt * 64 + wave * 16;

    __shared__ __bf16 Kt[2][64 * 64];    // [buf][row*64 + col], row = k-pos, 128 B rows
    __shared__ __bf16 Vt[2][64 * 64];    // [buf][row*64 + col], row = d,     col = s-chunk
    __shared__ __bf16 P[4][16 * 64];     // per-wave P tile, XOR-swizzled

    // staging lane geometry: instr j covers rows j*8..j*8+7; lane i -> row j*8 + (i>>3),
    // physical chunk i&7. Inverse-swizzled source chunk = (i&7) ^ (row&7) = (i&7)^(i>>3).
    int srow = lane >> 3;                // 0..7
    int cg = (lane & 7) ^ srow;          // global source chunk (involution of phys chunk)

    // Q fragments (A-layout: row = lane&15, k = (lane>>4)*8 + j)
    const __bf16* qrow = qb + ((size_t)(q0 + lc) * 8 + h) * 64 + lg * 8;
    bf16x8 qf0 = *(const bf16x8*)(qrow);
    bf16x8 qf1 = *(const bf16x8*)(qrow + 32);

    f32x4 o0 = {0,0,0,0}, o1 = {0,0,0,0}, o2 = {0,0,0,0}, o3 = {0,0,0,0};
    float m_[4] = {-3e38f, -3e38f, -3e38f, -3e38f};
    float l_[4] = {0.f, 0.f, 0.f, 0.f};

    const unsigned int* mprow[4];
#pragma unroll
    for (int r = 0; r < 4; ++r) mprow[r] = mp + (size_t)(q0 + lg * 4 + r) * 128;

    const __bf16* vbase = vt + (size_t)h * 64 * 4096;

    // ---- stage tile 0 ----
#pragma unroll
    for (int j = wave * 2; j < wave * 2 + 2; ++j) {
        gload_lds16(kb + (size_t)(j * 8 + srow) * 512 + h * 64 + cg * 8, &Kt[0][j * 512]);
        gload_lds16(vbase + (size_t)(j * 8 + srow) * 4096 + cg * 8,      &Vt[0][j * 512]);
    }
    __syncthreads();

    for (int step = 0; step < 64; ++step) {
        int cur = step & 1;
        int kb_i = step * 64;
        // ---- issue next tile's stage (lands before next iter's barrier exit) ----
        if (step < 63) {
            int nxt = kb_i + 64;
#pragma unroll
            for (int j = wave * 2; j < wave * 2 + 2; ++j) {
                gload_lds16(kb + (size_t)(nxt + j * 8 + srow) * 512 + h * 64 + cg * 8, &Kt[cur ^ 1][j * 512]);
                gload_lds16(vbase + (size_t)(j * 8 + srow) * 4096 + nxt + cg * 8,      &Vt[cur ^ 1][j * 512]);
            }
        }
        // ---- QK^T from LDS: 4 tiles of 16q x 16k ----
        const char* Kb = (const char*)&Kt[cur][0];
        f32x4 sc[4];
#pragma unroll
        for (int kc = 0; kc < 4; ++kc) {
            int row = kc * 16 + lc;
            int sw = (row & 7) << 4;
            bf16x8 kf0 = *(const bf16x8*)(Kb + ((row * 128 + lg * 16) ^ sw));
            bf16x8 kf1 = *(const bf16x8*)(Kb + ((row * 128 + 64 + lg * 16) ^ sw));
            f32x4 z = {0,0,0,0};
            z = __builtin_amdgcn_mfma_f32_16x16x32_bf16(qf0, kf0, z, 0, 0, 0);
            z = __builtin_amdgcn_mfma_f32_16x16x32_bf16(qf1, kf1, z, 0, 0, 0);
            sc[kc] = z;
        }
        // ---- mask (before scale) + online softmax ----
        float pv[4][4];   // [kc][r]
        float tmax[4];
#pragma unroll
        for (int r = 0; r < 4; ++r) {
            unsigned int w0 = mprow[r][(kb_i >> 5)];
            unsigned int w1 = mprow[r][(kb_i >> 5) + 1];
            float vmax = -3e38f;
#pragma unroll
            for (int kc = 0; kc < 4; ++kc) {
                unsigned int wsel = (kc < 2) ? w0 : w1;
                int bitpos = (kc & 1) * 16 + lc;
                float val = ((wsel >> bitpos) & 1u) ? sc[kc][r] * 0.125f : -1.25e19f;
                pv[kc][r] = val;
                vmax = fmaxf(vmax, val);
            }
            tmax[r] = vmax;
        }
#pragma unroll
        for (int r = 0; r < 4; ++r) {
            float v = tmax[r];
            v = fmaxf(v, __shfl_xor(v, 1));
            v = fmaxf(v, __shfl_xor(v, 2));
            v = fmaxf(v, __shfl_xor(v, 4));
            v = fmaxf(v, __shfl_xor(v, 8));
            float mn = fmaxf(m_[r], v);
            float corr = __expf(m_[r] - mn);
            m_[r] = mn;
            float ps = 0.f;
#pragma unroll
            for (int kc = 0; kc < 4; ++kc) {
                float p = __expf(pv[kc][r] - mn);
                pv[kc][r] = p;
                ps += p;
            }
            ps += __shfl_xor(ps, 1);
            ps += __shfl_xor(ps, 2);
            ps += __shfl_xor(ps, 4);
            ps += __shfl_xor(ps, 8);
            l_[r] = l_[r] * corr + ps;
            o0[r] *= corr; o1[r] *= corr; o2[r] *= corr; o3[r] *= corr;
        }
        // ---- write P (bf16) to per-wave swizzled LDS tile ----
        char* pbase = (char*)&P[wave][0];
#pragma unroll
        for (int kc = 0; kc < 4; ++kc)
#pragma unroll
            for (int r = 0; r < 4; ++r) {
                int row = lg * 4 + r, col = kc * 16 + lc;
                int byte = ((row * 64 + col) * 2) ^ ((row & 7) << 4);
                *(__bf16*)(pbase + byte) = (__bf16)pv[kc][r];
            }
        // ---- PV from LDS: O += P * V ----
        const char* Vb = (const char*)&Vt[cur][0];
        int swv = (lc & 7) << 4;
#pragma unroll
        for (int kk = 0; kk < 2; ++kk) {
            int pbyte = ((lc * 64 + kk * 32 + lg * 8) * 2) ^ swv;
            bf16x8 pf = *(const bf16x8*)((const char*)&P[wave][0] + pbyte);
            int ch = (kk * 4 + lg) * 16;
            o0 = __builtin_amdgcn_mfma_f32_16x16x32_bf16(pf, *(const bf16x8*)(Vb + (((0 * 16 + lc) * 128 + ch) ^ swv)), o0, 0, 0, 0);
            o1 = __builtin_amdgcn_mfma_f32_16x16x32_bf16(pf, *(const bf16x8*)(Vb + (((1 * 16 + lc) * 128 + ch) ^ swv)), o1, 0, 0, 0);
            o2 = __builtin_amdgcn_mfma_f32_16x16x32_bf16(pf, *(const bf16x8*)(Vb + (((2 * 16 + lc) * 128 + ch) ^ swv)), o2, 0, 0, 0);
            o3 = __builtin_amdgcn_mfma_f32_16x16x32_bf16(pf, *(const bf16x8*)(Vb + (((3 * 16 + lc) * 128 + ch) ^ swv)), o3, 0, 0, 0);
        }
        // ---- one barrier per step: drains staged loads (vmcnt) + protects buffer swap ----
        __syncthreads();
    }
    // ---- epilogue: normalize, write bf16 [s][h*64+d] ----
#pragma unroll
    for (int r = 0; r < 4; ++r) {
        float inv = 1.0f / l_[r];
        int row = q0 + lg * 4 + r;
        __bf16* dst = ao + (size_t)row * 512 + h * 64;
        dst[0 * 16 + lc] = (__bf16)(o0[r] * inv);
        dst[1 * 16 + lc] = (__bf16)(o1[r] * inv);
        dst[2 * 16 + lc] = (__bf16)(o2[r] * inv);
        dst[3 * 16 + lc] = (__bf16)(o3[r] * inv);
    }
}

// ---------------- final FC: out[s][n] = sum_k ao[s][k] * Wfc[n][k] + bfc[n] ----------------
__global__ __launch_bounds__(256) void fc_kernel(const __bf16* __restrict__ ao,
                                                 const __bf16* __restrict__ Wb,
                                                 const float* __restrict__ bfc,
                                                 float* __restrict__ out) {
    int bid = blockIdx.x;
    int stile = bid >> 3, nt = bid & 7;
    int t = threadIdx.x, wave = t >> 6, lane = t & 63, lg = lane >> 4, lc = lane & 15;
    int s0 = stile * 64 + wave * 16;
    int n0 = nt * 64;
    f32x4 c0 = {0,0,0,0}, c1 = {0,0,0,0}, c2 = {0,0,0,0}, c3 = {0,0,0,0};
    for (int k0 = 0; k0 < 512; k0 += 32) {
        bf16x8 af = *(const bf16x8*)(ao + (size_t)(s0 + lc) * 512 + k0 + lg * 8);
        const __bf16* wb = Wb + k0 + lg * 8;
        c0 = __builtin_amdgcn_mfma_f32_16x16x32_bf16(af, *(const bf16x8*)(wb + (size_t)(n0 + 0 * 16 + lc) * 512), c0, 0, 0, 0);
        c1 = __builtin_amdgcn_mfma_f32_16x16x32_bf16(af, *(const bf16x8*)(wb + (size_t)(n0 + 1 * 16 + lc) * 512), c1, 0, 0, 0);
        c2 = __builtin_amdgcn_mfma_f32_16x16x32_bf16(af, *(const bf16x8*)(wb + (size_t)(n0 + 2 * 16 + lc) * 512), c2, 0, 0, 0);
        c3 = __builtin_amdgcn_mfma_f32_16x16x32_bf16(af, *(const bf16x8*)(wb + (size_t)(n0 + 3 * 16 + lc) * 512), c3, 0, 0, 0);
    }
#pragma unroll
    for (int r = 0; r < 4; ++r) {
        int row = s0 + lg * 4 + r;
        float* dst = out + (size_t)row * 512 + n0;
        dst[0 * 16 + lc] = c0[r] + bfc[n0 + 0 * 16 + lc];
        dst[1 * 16 + lc] = c1[r] + bfc[n0 + 1 * 16 + lc];
        dst[2 * 16 + lc] = c2[r] + bfc[n0 + 2 * 16 + lc];
        dst[3 * 16 + lc] = c3[r] + bfc[n0 + 3 * 16 + lc];
    }
}

extern "C" void kernel_launch(void* const* d_in, const int* in_sizes, int n_in,
                              void* d_out, int out_size, void* d_ws, size_t ws_size,
                              hipStream_t stream) {
    const float* query = (const float*)d_in[0];
    const float* key   = (const float*)d_in[1];
    const float* value = (const float*)d_in[2];
    const int*   mask  = (const int*)d_in[3];
    const float* Wq  = (const float*)d_in[4];
    const float* bq  = (const float*)d_in[5];
    const float* Wk  = (const float*)d_in[6];
    const float* bk  = (const float*)d_in[7];
    const float* Wv  = (const float*)d_in[8];
    const float* bv  = (const float*)d_in[9];
    const float* Wfc = (const float*)d_in[10];
    const float* bfc = (const float*)d_in[11];

    char* ws = (char*)d_ws;
    const size_t MB = 1024 * 1024;
    __bf16* q_bf   = (__bf16*)(ws + 0 * MB);      // 4 MB  [S][H][64]
    __bf16* k_bf   = (__bf16*)(ws + 4 * MB);      // 4 MB  [S][H][64]
    __bf16* vt     = (__bf16*)(ws + 8 * MB);      // 4 MB  [H][64][S]
    __bf16* ao     = (__bf16*)(ws + 12 * MB);     // 4 MB  [S][512]
    __bf16* wfc_bf = (__bf16*)(ws + 16 * MB);     // 0.5 MB
    unsigned int* mpack = (unsigned int*)(ws + 17 * MB);  // 2 MB [S][128]

    proj_kernel<<<8192, 256, 0, stream>>>(query, Wq, bq, q_bf);
    proj_kernel<<<8192, 256, 0, stream>>>(key, Wk, bk, k_bf);
    proj_v_kernel<<<512, 256, 0, stream>>>(value, Wv, bv, vt);
    maskpack_kernel<<<65536, 256, 0, stream>>>(mask, mpack);
    cvt_kernel<<<1024, 256, 0, stream>>>(Wfc, wfc_bf, 262144);
    attn_kernel<<<512, 256, 0, stream>>>(q_bf, k_bf, vt, mpack, ao);
    fc_kernel<<<512, 256, 0, stream>>>(ao, wfc_bf, bfc, (float*)d_out);
}

// Round 4
// 140.039 us; speedup vs baseline: 3.8058x; 2.2088x over previous
//
#include <hip/hip_runtime.h>
#include <hip/hip_bf16.h>

#define S_LEN 4096
#define DMODEL 512
#define NHEAD 8
#define HDIM 64

typedef __bf16 bf16x8 __attribute__((ext_vector_type(8)));
typedef __bf16 bf16x4 __attribute__((ext_vector_type(4)));
typedef float f32x4 __attribute__((ext_vector_type(4)));

__device__ __forceinline__ void gload_lds16(const void* g, void* l) {
    __builtin_amdgcn_global_load_lds((const __attribute__((address_space(1))) void*)g,
                                     (__attribute__((address_space(3))) void*)l, 16, 0, 0);
}

// ---------------- fused q/k projection (MFMA): rows = (s,h) flat, W shared across heads ----------------
__global__ __launch_bounds__(256) void proj_qk_kernel(const float* __restrict__ xq,
                                                      const float* __restrict__ xk,
                                                      const float* __restrict__ Wq,
                                                      const float* __restrict__ bq,
                                                      const float* __restrict__ Wk,
                                                      const float* __restrict__ bk,
                                                      __bf16* __restrict__ yq,
                                                      __bf16* __restrict__ yk) {
    int t = threadIdx.x, wave = t >> 6, lane = t & 63, lg = lane >> 4, lc = lane & 15;
    int r0 = blockIdx.x * 64 + wave * 16;
    const float* xrq = xq + (size_t)(r0 + lc) * 64 + lg * 8;
    const float* xrk = xk + (size_t)(r0 + lc) * 64 + lg * 8;
    bf16x8 aq[2], ak[2];
#pragma unroll
    for (int c = 0; c < 2; ++c) {
        f32x4 u0 = *(const f32x4*)(xrq + c * 32);
        f32x4 u1 = *(const f32x4*)(xrq + c * 32 + 4);
        f32x4 v0 = *(const f32x4*)(xrk + c * 32);
        f32x4 v1 = *(const f32x4*)(xrk + c * 32 + 4);
        bf16x8 a, b;
#pragma unroll
        for (int j = 0; j < 4; ++j) {
            a[j] = (__bf16)u0[j]; a[4 + j] = (__bf16)u1[j];
            b[j] = (__bf16)v0[j]; b[4 + j] = (__bf16)v1[j];
        }
        aq[c] = a; ak[c] = b;
    }
#pragma unroll
    for (int nt = 0; nt < 4; ++nt) {
        const float* wq = Wq + (size_t)(nt * 16 + lc) * 64 + lg * 8;
        const float* wk = Wk + (size_t)(nt * 16 + lc) * 64 + lg * 8;
        f32x4 cq = {0, 0, 0, 0}, ck = {0, 0, 0, 0};
#pragma unroll
        for (int c = 0; c < 2; ++c) {
            f32x4 u0 = *(const f32x4*)(wq + c * 32);
            f32x4 u1 = *(const f32x4*)(wq + c * 32 + 4);
            f32x4 v0 = *(const f32x4*)(wk + c * 32);
            f32x4 v1 = *(const f32x4*)(wk + c * 32 + 4);
            bf16x8 bw, bw2;
#pragma unroll
            for (int j = 0; j < 4; ++j) {
                bw[j] = (__bf16)u0[j]; bw[4 + j] = (__bf16)u1[j];
                bw2[j] = (__bf16)v0[j]; bw2[4 + j] = (__bf16)v1[j];
            }
            cq = __builtin_amdgcn_mfma_f32_16x16x32_bf16(aq[c], bw, cq, 0, 0, 0);
            ck = __builtin_amdgcn_mfma_f32_16x16x32_bf16(ak[c], bw2, ck, 0, 0, 0);
        }
        float bqv = bq[nt * 16 + lc], bkv = bk[nt * 16 + lc];
#pragma unroll
        for (int r = 0; r < 4; ++r) {
            yq[(size_t)(r0 + lg * 4 + r) * 64 + nt * 16 + lc] = (__bf16)(cq[r] + bqv);
            yk[(size_t)(r0 + lg * 4 + r) * 64 + nt * 16 + lc] = (__bf16)(ck[r] + bkv);
        }
    }
}

// ---------------- v projection (MFMA) with transpose to vt[h][d][s] ----------------
__global__ __launch_bounds__(256) void proj_v_kernel(const float* __restrict__ x,
                                                     const float* __restrict__ W,
                                                     const float* __restrict__ b,
                                                     __bf16* __restrict__ vt) {
    __shared__ float T[64][65];
    int h = blockIdx.x & 7, s0 = (blockIdx.x >> 3) * 64;
    int t = threadIdx.x, wave = t >> 6, lane = t & 63, lg = lane >> 4, lc = lane & 15;
    const float* xr = x + ((size_t)(s0 + wave * 16 + lc) * 8 + h) * 64 + lg * 8;
    bf16x8 av[2];
#pragma unroll
    for (int c = 0; c < 2; ++c) {
        f32x4 u0 = *(const f32x4*)(xr + c * 32);
        f32x4 u1 = *(const f32x4*)(xr + c * 32 + 4);
        bf16x8 a;
#pragma unroll
        for (int j = 0; j < 4; ++j) { a[j] = (__bf16)u0[j]; a[4 + j] = (__bf16)u1[j]; }
        av[c] = a;
    }
#pragma unroll
    for (int nt = 0; nt < 4; ++nt) {
        const float* wv = W + (size_t)(nt * 16 + lc) * 64 + lg * 8;
        f32x4 cv = {0, 0, 0, 0};
#pragma unroll
        for (int c = 0; c < 2; ++c) {
            f32x4 u0 = *(const f32x4*)(wv + c * 32);
            f32x4 u1 = *(const f32x4*)(wv + c * 32 + 4);
            bf16x8 bw;
#pragma unroll
            for (int j = 0; j < 4; ++j) { bw[j] = (__bf16)u0[j]; bw[4 + j] = (__bf16)u1[j]; }
            cv = __builtin_amdgcn_mfma_f32_16x16x32_bf16(av[c], bw, cv, 0, 0, 0);
        }
        float bvv = b[nt * 16 + lc];
#pragma unroll
        for (int r = 0; r < 4; ++r) T[wave * 16 + lg * 4 + r][nt * 16 + lc] = cv[r] + bvv;
    }
    __syncthreads();
    int d = t >> 2, qr = t & 3;
    bf16x8 w0, w1;
#pragma unroll
    for (int i = 0; i < 8; ++i) {
        w0[i] = (__bf16)T[qr * 16 + i][d];
        w1[i] = (__bf16)T[qr * 16 + 8 + i][d];
    }
    __bf16* dst = vt + ((size_t)h * 64 + d) * 4096 + s0 + qr * 16;
    *(bf16x8*)(dst) = w0;
    *(bf16x8*)(dst + 8) = w1;
}

// ---------------- mask packing (grid-stride): pack bit ki = (mask[qi][ki] != 0) ----------------
__global__ __launch_bounds__(256) void maskpack_kernel(const int* __restrict__ mask,
                                                       unsigned int* __restrict__ pack) {
    int t = threadIdx.x, lane = t & 63;
    int wid = blockIdx.x * 4 + (t >> 6);          // 8192 waves
#pragma unroll 4
    for (int it = 0; it < 32; ++it) {
        int gw = wid * 32 + it;                   // (qi,seg) pair, 262144 total
        int qi = gw >> 6, seg = gw & 63;
        unsigned long long bits = __ballot(mask[(size_t)qi * 4096 + seg * 64 + lane] != 0);
        if (lane == 0)
            *(unsigned long long*)(&pack[(size_t)qi * 128 + seg * 2]) = bits;
    }
}

// ---------------- f32 -> bf16 convert ----------------
__global__ __launch_bounds__(256) void cvt_kernel(const float* __restrict__ src,
                                                  __bf16* __restrict__ dst, int n) {
    int i = blockIdx.x * 256 + threadIdx.x;
    if (i < n) dst[i] = (__bf16)src[i];
}

// ---------------- flash attention: LDS-staged, swapped-QK softmax, defer-max, split-KV ----------------
// block: h = bid&7 (head -> XCD), qt = (bid>>3)&63, sp = bid>>9
__global__ __launch_bounds__(256, 4) void attn_kernel(const __bf16* __restrict__ qb,
                                                      const __bf16* __restrict__ kb,
                                                      const __bf16* __restrict__ vt,
                                                      const unsigned int* __restrict__ mp,
                                                      int kv_len,
                                                      float* __restrict__ opart,
                                                      float* __restrict__ stats,
                                                      __bf16* __restrict__ ao) {
    int bid = blockIdx.x;
    int h = bid & 7, qt = (bid >> 3) & 63, sp = bid >> 9;
    int kv0 = sp * kv_len;
    int t = threadIdx.x, wave = t >> 6, lane = t & 63, lg = lane >> 4, lc = lane & 15;
    int q0 = qt * 64 + wave * 16;

    __shared__ __bf16 Kt[2][64 * 64];    // [buf][krow*64 + d], 128 B rows, XOR-swizzled
    __shared__ __bf16 Vt[2][64 * 64];    // [buf][drow*64 + s-chunk], XOR-swizzled
    __shared__ __bf16 P[4][16 * 64];     // per-wave P tile [q][k], XOR-swizzled

    int srow = lane >> 3;                // staging row-within-8
    int cg = (lane & 7) ^ srow;          // inverse-swizzled global source chunk

    const __bf16* qrow = qb + ((size_t)(q0 + lc) * 8 + h) * 64 + lg * 8;
    bf16x8 qf0 = *(const bf16x8*)(qrow);
    bf16x8 qf1 = *(const bf16x8*)(qrow + 32);

    f32x4 o0 = {0,0,0,0}, o1 = {0,0,0,0}, o2 = {0,0,0,0}, o3 = {0,0,0,0};
    float m_ = -3e38f, l_ = 0.f;         // per-lane stats for q = q0 + lc

    const unsigned int* mrow = mp + (size_t)(q0 + lc) * 128;
    const __bf16* vbase = vt + (size_t)h * 64 * 4096;

    // ---- stage tile 0 ----
#pragma unroll
    for (int j = wave * 2; j < wave * 2 + 2; ++j) {
        gload_lds16(kb + (size_t)(kv0 + j * 8 + srow) * 512 + h * 64 + cg * 8, &Kt[0][j * 512]);
        gload_lds16(vbase + (size_t)(j * 8 + srow) * 4096 + kv0 + cg * 8,      &Vt[0][j * 512]);
    }
    __syncthreads();

    int nsteps = kv_len >> 6;
    for (int step = 0; step < nsteps; ++step) {
        int cur = step & 1;
        int kb_i = kv0 + step * 64;
        if (step < nsteps - 1) {
            int nxt = kb_i + 64;
#pragma unroll
            for (int j = wave * 2; j < wave * 2 + 2; ++j) {
                gload_lds16(kb + (size_t)(nxt + j * 8 + srow) * 512 + h * 64 + cg * 8, &Kt[cur ^ 1][j * 512]);
                gload_lds16(vbase + (size_t)(j * 8 + srow) * 4096 + nxt + cg * 8,      &Vt[cur ^ 1][j * 512]);
            }
        }
        // ---- QK^T swapped: sc[kc][r] = score[k = kb_i+kc*16+lg*4+r][q = q0+lc] ----
        const char* Kb = (const char*)&Kt[cur][0];
        f32x4 sc[4];
#pragma unroll
        for (int kc = 0; kc < 4; ++kc) {
            int row = kc * 16 + lc;
            int sw = (row & 7) << 4;
            bf16x8 kf0 = *(const bf16x8*)(Kb + ((row * 128 + lg * 16) ^ sw));
            bf16x8 kf1 = *(const bf16x8*)(Kb + ((row * 128 + 64 + lg * 16) ^ sw));
            f32x4 z = {0,0,0,0};
            z = __builtin_amdgcn_mfma_f32_16x16x32_bf16(kf0, qf0, z, 0, 0, 0);
            z = __builtin_amdgcn_mfma_f32_16x16x32_bf16(kf1, qf1, z, 0, 0, 0);
            sc[kc] = z;
        }
        // ---- mask (before scale) + per-lane row softmax ----
        unsigned int w0 = mrow[kb_i >> 5], w1 = mrow[(kb_i >> 5) + 1];
        float vals[4][4];
        float vmax = -3e38f;
#pragma unroll
        for (int kc = 0; kc < 4; ++kc) {
            unsigned int wsel = (kc < 2) ? w0 : w1;
#pragma unroll
            for (int r = 0; r < 4; ++r) {
                int bitpos = (kc & 1) * 16 + lg * 4 + r;
                float val = ((wsel >> bitpos) & 1u) ? sc[kc][r] * 0.125f : -1.25e19f;
                vals[kc][r] = val;
                vmax = fmaxf(vmax, val);
            }
        }
        vmax = fmaxf(vmax, __shfl_xor(vmax, 16));
        vmax = fmaxf(vmax, __shfl_xor(vmax, 32));
        // ---- defer-max rescale (rare) ----
        if (__any(vmax > m_ + 8.0f)) {
            float mn = fmaxf(m_, vmax);
            float corr = __expf(m_ - mn);
            m_ = mn;
            l_ *= corr;
            f32x4 cv;
#pragma unroll
            for (int r = 0; r < 4; ++r) cv[r] = __shfl(corr, lg * 4 + r);
            o0 *= cv; o1 *= cv; o2 *= cv; o3 *= cv;
        }
        float ps = 0.f;
#pragma unroll
        for (int kc = 0; kc < 4; ++kc)
#pragma unroll
            for (int r = 0; r < 4; ++r) {
                float p = __expf(vals[kc][r] - m_);
                vals[kc][r] = p;
                ps += p;
            }
        ps += __shfl_xor(ps, 16);
        ps += __shfl_xor(ps, 32);
        l_ += ps;
        // ---- write P[q=lc][k] packed bf16x4, swizzled ----
        char* pbase = (char*)&P[wave][0];
#pragma unroll
        for (int kc = 0; kc < 4; ++kc) {
            bf16x4 pk;
#pragma unroll
            for (int r = 0; r < 4; ++r) pk[r] = (__bf16)vals[kc][r];
            int byte = (lc * 128 + kc * 32 + lg * 8) ^ ((lc & 7) << 4);
            *(bf16x4*)(pbase + byte) = pk;
        }
        // ---- PV: O += P * V ----
        const char* Vb = (const char*)&Vt[cur][0];
        int swv = (lc & 7) << 4;
#pragma unroll
        for (int kk = 0; kk < 2; ++kk) {
            int pbyte = ((lc * 64 + kk * 32 + lg * 8) * 2) ^ swv;
            bf16x8 pf = *(const bf16x8*)((const char*)&P[wave][0] + pbyte);
            int ch = (kk * 4 + lg) * 16;
            o0 = __builtin_amdgcn_mfma_f32_16x16x32_bf16(pf, *(const bf16x8*)(Vb + (((0 * 16 + lc) * 128 + ch) ^ swv)), o0, 0, 0, 0);
            o1 = __builtin_amdgcn_mfma_f32_16x16x32_bf16(pf, *(const bf16x8*)(Vb + (((1 * 16 + lc) * 128 + ch) ^ swv)), o1, 0, 0, 0);
            o2 = __builtin_amdgcn_mfma_f32_16x16x32_bf16(pf, *(const bf16x8*)(Vb + (((2 * 16 + lc) * 128 + ch) ^ swv)), o2, 0, 0, 0);
            o3 = __builtin_amdgcn_mfma_f32_16x16x32_bf16(pf, *(const bf16x8*)(Vb + (((3 * 16 + lc) * 128 + ch) ^ swv)), o3, 0, 0, 0);
        }
        __syncthreads();
    }
    if (opart) {
        if (lg == 0) {
            size_t rh = (size_t)sp * 32768 + (size_t)(q0 + lc) * 8 + h;
            stats[rh * 2]     = m_;
            stats[rh * 2 + 1] = l_;
        }
#pragma unroll
        for (int r = 0; r < 4; ++r) {
            size_t rh = (size_t)sp * 32768 + (size_t)(q0 + lg * 4 + r) * 8 + h;
            float* dst = opart + rh * 64;
            dst[0 * 16 + lc] = o0[r];
            dst[1 * 16 + lc] = o1[r];
            dst[2 * 16 + lc] = o2[r];
            dst[3 * 16 + lc] = o3[r];
        }
    } else {
        float linv = 1.0f / l_;
#pragma unroll
        for (int r = 0; r < 4; ++r) {
            float inv = __shfl(linv, lg * 4 + r);
            int row = q0 + lg * 4 + r;
            __bf16* dst = ao + (size_t)row * 512 + h * 64;
            dst[0 * 16 + lc] = (__bf16)(o0[r] * inv);
            dst[1 * 16 + lc] = (__bf16)(o1[r] * inv);
            dst[2 * 16 + lc] = (__bf16)(o2[r] * inv);
            dst[3 * 16 + lc] = (__bf16)(o3[r] * inv);
        }
    }
}

// ---------------- split-KV combine ----------------
__global__ __launch_bounds__(256) void combine_kernel(const float* __restrict__ opart,
                                                      const float* __restrict__ stats,
                                                      __bf16* __restrict__ ao, int nsplit) {
    int t = threadIdx.x, lane = t & 63, w = t >> 6;
    int rh = blockIdx.x * 4 + w;     // row*8 + h
    float m_i[4], l_i[4];
    float M = -3e38f;
#pragma unroll 4
    for (int sp = 0; sp < nsplit; ++sp) {
        m_i[sp] = stats[((size_t)sp * 32768 + rh) * 2];
        l_i[sp] = stats[((size_t)sp * 32768 + rh) * 2 + 1];
        M = fmaxf(M, m_i[sp]);
    }
    float L = 0.f, acc = 0.f;
#pragma unroll 4
    for (int sp = 0; sp < nsplit; ++sp) {
        float scl = __expf(m_i[sp] - M);
        L += l_i[sp] * scl;
        acc += opart[((size_t)sp * 32768 + rh) * 64 + lane] * scl;
    }
    int row = rh >> 3, h = rh & 7;
    ao[(size_t)row * 512 + h * 64 + lane] = (__bf16)(acc / L);
}

// ---------------- final FC: out[s][n] = sum_k ao[s][k] * Wfc[n][k] + bfc[n] ----------------
__global__ __launch_bounds__(256) void fc_kernel(const __bf16* __restrict__ ao,
                                                 const __bf16* __restrict__ Wb,
                                                 const float* __restrict__ bfc,
                                                 float* __restrict__ out) {
    int bid = blockIdx.x;
    int stile = bid >> 3, nt = bid & 7;
    int t = threadIdx.x, wave = t >> 6, lane = t & 63, lg = lane >> 4, lc = lane & 15;
    int s0 = stile * 64 + wave * 16;
    int n0 = nt * 64;
    f32x4 c0 = {0,0,0,0}, c1 = {0,0,0,0}, c2 = {0,0,0,0}, c3 = {0,0,0,0};
    for (int k0 = 0; k0 < 512; k0 += 32) {
        bf16x8 af = *(const bf16x8*)(ao + (size_t)(s0 + lc) * 512 + k0 + lg * 8);
        const __bf16* wb = Wb + k0 + lg * 8;
        c0 = __builtin_amdgcn_mfma_f32_16x16x32_bf16(af, *(const bf16x8*)(wb + (size_t)(n0 + 0 * 16 + lc) * 512), c0, 0, 0, 0);
        c1 = __builtin_amdgcn_mfma_f32_16x16x32_bf16(af, *(const bf16x8*)(wb + (size_t)(n0 + 1 * 16 + lc) * 512), c1, 0, 0, 0);
        c2 = __builtin_amdgcn_mfma_f32_16x16x32_bf16(af, *(const bf16x8*)(wb + (size_t)(n0 + 2 * 16 + lc) * 512), c2, 0, 0, 0);
        c3 = __builtin_amdgcn_mfma_f32_16x16x32_bf16(af, *(const bf16x8*)(wb + (size_t)(n0 + 3 * 16 + lc) * 512), c3, 0, 0, 0);
    }
#pragma unroll
    for (int r = 0; r < 4; ++r) {
        int row = s0 + lg * 4 + r;
        float* dst = out + (size_t)row * 512 + n0;
        dst[0 * 16 + lc] = c0[r] + bfc[n0 + 0 * 16 + lc];
        dst[1 * 16 + lc] = c1[r] + bfc[n0 + 1 * 16 + lc];
        dst[2 * 16 + lc] = c2[r] + bfc[n0 + 2 * 16 + lc];
        dst[3 * 16 + lc] = c3[r] + bfc[n0 + 3 * 16 + lc];
    }
}

extern "C" void kernel_launch(void* const* d_in, const int* in_sizes, int n_in,
                              void* d_out, int out_size, void* d_ws, size_t ws_size,
                              hipStream_t stream) {
    const float* query = (const float*)d_in[0];
    const float* key   = (const float*)d_in[1];
    const float* value = (const float*)d_in[2];
    const int*   mask  = (const int*)d_in[3];
    const float* Wq  = (const float*)d_in[4];
    const float* bq  = (const float*)d_in[5];
    const float* Wk  = (const float*)d_in[6];
    const float* bk  = (const float*)d_in[7];
    const float* Wv  = (const float*)d_in[8];
    const float* bv  = (const float*)d_in[9];
    const float* Wfc = (const float*)d_in[10];
    const float* bfc = (const float*)d_in[11];

    char* ws = (char*)d_ws;
    const size_t MB = 1024 * 1024;
    __bf16* q_bf   = (__bf16*)(ws + 0 * MB);      // 4 MB  [S*H][64]
    __bf16* k_bf   = (__bf16*)(ws + 4 * MB);      // 4 MB  [S*H][64]
    __bf16* vt     = (__bf16*)(ws + 8 * MB);      // 4 MB  [H][64][S]
    __bf16* ao     = (__bf16*)(ws + 12 * MB);     // 4 MB  [S][512]
    __bf16* wfc_bf = (__bf16*)(ws + 16 * MB);     // 0.5 MB
    unsigned int* mpack = (unsigned int*)(ws + 17 * MB);  // 2 MB [S][128]
    const size_t base = 19 * MB;
    int nsplit = (ws_size >= base + 2 * (8 * MB) + 524288) ? 2 : 1;
    float* opart = (float*)(ws + base);
    float* stats = (float*)(ws + base + (size_t)nsplit * 8 * MB);

    proj_qk_kernel<<<512, 256, 0, stream>>>(query, key, Wq, bq, Wk, bk, q_bf, k_bf);
    proj_v_kernel<<<512, 256, 0, stream>>>(value, Wv, bv, vt);
    maskpack_kernel<<<2048, 256, 0, stream>>>(mask, mpack);
    cvt_kernel<<<1024, 256, 0, stream>>>(Wfc, wfc_bf, 262144);
    if (nsplit > 1) {
        attn_kernel<<<512 * nsplit, 256, 0, stream>>>(q_bf, k_bf, vt, mpack,
                                                      S_LEN / nsplit, opart, stats, ao);
        combine_kernel<<<8192, 256, 0, stream>>>(opart, stats, ao, nsplit);
    } else {
        attn_kernel<<<512, 256, 0, stream>>>(q_bf, k_bf, vt, mpack,
                                             S_LEN, nullptr, nullptr, ao);
    }
    fc_kernel<<<512, 256, 0, stream>>>(ao, wfc_bf, bfc, (float*)d_out);
}

// Round 5
// 124.212 us; speedup vs baseline: 4.2908x; 1.1274x over previous
//
#include <hip/hip_runtime.h>
#include <hip/hip_bf16.h>

#define S_LEN 4096
#define DMODEL 512
#define NHEAD 8
#define HDIM 64

typedef __bf16 bf16x8 __attribute__((ext_vector_type(8)));
typedef __bf16 bf16x4 __attribute__((ext_vector_type(4)));
typedef float f32x4 __attribute__((ext_vector_type(4)));

#define S2EXP 0.18033688011112042f   // 0.125 * log2(e)

__device__ __forceinline__ void gload_lds16(const void* g, void* l) {
    __builtin_amdgcn_global_load_lds((const __attribute__((address_space(1))) void*)g,
                                     (__attribute__((address_space(3))) void*)l, 16, 0, 0);
}

// ---------------- fused projections: blocks 0-511 q+k, 512-1023 v(+transpose) ----------------
__global__ __launch_bounds__(256) void proj_all_kernel(const float* __restrict__ xq,
                                                       const float* __restrict__ xk,
                                                       const float* __restrict__ xv,
                                                       const float* __restrict__ Wq,
                                                       const float* __restrict__ bq,
                                                       const float* __restrict__ Wk,
                                                       const float* __restrict__ bk,
                                                       const float* __restrict__ Wv,
                                                       const float* __restrict__ bv,
                                                       __bf16* __restrict__ yq,
                                                       __bf16* __restrict__ yk,
                                                       __bf16* __restrict__ vt) {
    __shared__ float T[64][65];
    int bid = blockIdx.x;
    int t = threadIdx.x, wave = t >> 6, lane = t & 63, lg = lane >> 4, lc = lane & 15;
    if (bid < 512) {
        int r0 = bid * 64 + wave * 16;
        const float* xrq = xq + (size_t)(r0 + lc) * 64 + lg * 8;
        const float* xrk = xk + (size_t)(r0 + lc) * 64 + lg * 8;
        bf16x8 aq[2], ak[2];
#pragma unroll
        for (int c = 0; c < 2; ++c) {
            f32x4 u0 = *(const f32x4*)(xrq + c * 32);
            f32x4 u1 = *(const f32x4*)(xrq + c * 32 + 4);
            f32x4 v0 = *(const f32x4*)(xrk + c * 32);
            f32x4 v1 = *(const f32x4*)(xrk + c * 32 + 4);
            bf16x8 a, b;
#pragma unroll
            for (int j = 0; j < 4; ++j) {
                a[j] = (__bf16)u0[j]; a[4 + j] = (__bf16)u1[j];
                b[j] = (__bf16)v0[j]; b[4 + j] = (__bf16)v1[j];
            }
            aq[c] = a; ak[c] = b;
        }
#pragma unroll
        for (int nt = 0; nt < 4; ++nt) {
            const float* wq = Wq + (size_t)(nt * 16 + lc) * 64 + lg * 8;
            const float* wk = Wk + (size_t)(nt * 16 + lc) * 64 + lg * 8;
            f32x4 cq = {0, 0, 0, 0}, ck = {0, 0, 0, 0};
#pragma unroll
            for (int c = 0; c < 2; ++c) {
                f32x4 u0 = *(const f32x4*)(wq + c * 32);
                f32x4 u1 = *(const f32x4*)(wq + c * 32 + 4);
                f32x4 v0 = *(const f32x4*)(wk + c * 32);
                f32x4 v1 = *(const f32x4*)(wk + c * 32 + 4);
                bf16x8 bw, bw2;
#pragma unroll
                for (int j = 0; j < 4; ++j) {
                    bw[j] = (__bf16)u0[j]; bw[4 + j] = (__bf16)u1[j];
                    bw2[j] = (__bf16)v0[j]; bw2[4 + j] = (__bf16)v1[j];
                }
                cq = __builtin_amdgcn_mfma_f32_16x16x32_bf16(aq[c], bw, cq, 0, 0, 0);
                ck = __builtin_amdgcn_mfma_f32_16x16x32_bf16(ak[c], bw2, ck, 0, 0, 0);
            }
            float bqv = bq[nt * 16 + lc], bkv = bk[nt * 16 + lc];
#pragma unroll
            for (int r = 0; r < 4; ++r) {
                yq[(size_t)(r0 + lg * 4 + r) * 64 + nt * 16 + lc] = (__bf16)(cq[r] + bqv);
                yk[(size_t)(r0 + lg * 4 + r) * 64 + nt * 16 + lc] = (__bf16)(ck[r] + bkv);
            }
        }
    } else {
        int vb = bid - 512;
        int h = vb & 7, s0 = (vb >> 3) * 64;
        const float* xr = xv + ((size_t)(s0 + wave * 16 + lc) * 8 + h) * 64 + lg * 8;
        bf16x8 av[2];
#pragma unroll
        for (int c = 0; c < 2; ++c) {
            f32x4 u0 = *(const f32x4*)(xr + c * 32);
            f32x4 u1 = *(const f32x4*)(xr + c * 32 + 4);
            bf16x8 a;
#pragma unroll
            for (int j = 0; j < 4; ++j) { a[j] = (__bf16)u0[j]; a[4 + j] = (__bf16)u1[j]; }
            av[c] = a;
        }
#pragma unroll
        for (int nt = 0; nt < 4; ++nt) {
            const float* wv = Wv + (size_t)(nt * 16 + lc) * 64 + lg * 8;
            f32x4 cv = {0, 0, 0, 0};
#pragma unroll
            for (int c = 0; c < 2; ++c) {
                f32x4 u0 = *(const f32x4*)(wv + c * 32);
                f32x4 u1 = *(const f32x4*)(wv + c * 32 + 4);
                bf16x8 bw;
#pragma unroll
                for (int j = 0; j < 4; ++j) { bw[j] = (__bf16)u0[j]; bw[4 + j] = (__bf16)u1[j]; }
                cv = __builtin_amdgcn_mfma_f32_16x16x32_bf16(av[c], bw, cv, 0, 0, 0);
            }
            float bvv = bv[nt * 16 + lc];
#pragma unroll
            for (int r = 0; r < 4; ++r) T[wave * 16 + lg * 4 + r][nt * 16 + lc] = cv[r] + bvv;
        }
        __syncthreads();
        int d = t >> 2, qr = t & 3;
        bf16x8 w0, w1;
#pragma unroll
        for (int i = 0; i < 8; ++i) {
            w0[i] = (__bf16)T[qr * 16 + i][d];
            w1[i] = (__bf16)T[qr * 16 + 8 + i][d];
        }
        __bf16* dst = vt + ((size_t)h * 64 + d) * 4096 + s0 + qr * 16;
        *(bf16x8*)(dst) = w0;
        *(bf16x8*)(dst + 8) = w1;
    }
}

// ---------------- prep: blocks 0-2047 mask packing, 2048-2079 Wfc f32->bf16 ----------------
__global__ __launch_bounds__(256) void prep_kernel(const int* __restrict__ mask,
                                                   unsigned int* __restrict__ pack,
                                                   const float* __restrict__ Wfc,
                                                   __bf16* __restrict__ wfc_bf) {
    int bid = blockIdx.x;
    int t = threadIdx.x;
    if (bid < 2048) {
        int lane = t & 63;
        int wid = bid * 4 + (t >> 6);
#pragma unroll 4
        for (int it = 0; it < 32; ++it) {
            int gw = wid * 32 + it;
            int qi = gw >> 6, seg = gw & 63;
            unsigned long long bits = __ballot(mask[(size_t)qi * 4096 + seg * 64 + lane] != 0);
            if (lane == 0)
                *(unsigned long long*)(&pack[(size_t)qi * 128 + seg * 2]) = bits;
        }
    } else {
        int b = bid - 2048;
        const f32x4* s4 = (const f32x4*)Wfc;
#pragma unroll
        for (int i = 0; i < 8; ++i) {
            int idx = (b * 8 + i) * 256 + t;     // f32x4 index, 65536 total
            f32x4 v = s4[idx];
            bf16x4 o;
#pragma unroll
            for (int j = 0; j < 4; ++j) o[j] = (__bf16)v[j];
            *(bf16x4*)(wfc_bf + (size_t)idx * 4) = o;
        }
    }
}

// ---------------- flash attention: no-max softmax, AND-mask, l via ones-MFMA ----------------
// block: h = bid&7 (head -> XCD), qt = (bid>>3)&63, sp = bid>>9
__global__ __launch_bounds__(256, 4) void attn_kernel(const __bf16* __restrict__ qb,
                                                      const __bf16* __restrict__ kb,
                                                      const __bf16* __restrict__ vt,
                                                      const unsigned int* __restrict__ mp,
                                                      int kv_len,
                                                      float* __restrict__ opart,
                                                      float* __restrict__ stats,
                                                      __bf16* __restrict__ ao) {
    int bid = blockIdx.x;
    int h = bid & 7, qt = (bid >> 3) & 63, sp = bid >> 9;
    int kv0 = sp * kv_len;
    int t = threadIdx.x, wave = t >> 6, lane = t & 63, lg = lane >> 4, lc = lane & 15;
    int q0 = qt * 64 + wave * 16;

    __shared__ __bf16 Kt[2][64 * 64];    // [buf][krow*64 + d], XOR-swizzled
    __shared__ __bf16 Vt[2][64 * 64];    // [buf][drow*64 + s-chunk], XOR-swizzled
    __shared__ __bf16 P[4][16 * 64];     // per-wave P tile [q][k], XOR-swizzled

    int srow = lane >> 3;
    int cg = (lane & 7) ^ srow;          // inverse-swizzled global source chunk

    const __bf16* qrow = qb + ((size_t)(q0 + lc) * 8 + h) * 64 + lg * 8;
    bf16x8 qf0 = *(const bf16x8*)(qrow);
    bf16x8 qf1 = *(const bf16x8*)(qrow + 32);

    bf16x8 onesf;
#pragma unroll
    for (int j = 0; j < 8; ++j) onesf[j] = (__bf16)1.0f;

    f32x4 o0 = {0,0,0,0}, o1 = {0,0,0,0}, o2 = {0,0,0,0}, o3 = {0,0,0,0};
    f32x4 l_acc = {0,0,0,0};             // row-sum of P via ones-MFMA; l_acc[r] = l[q0+lg*4+r]

    const unsigned int* mrow = mp + (size_t)(q0 + lc) * 128;
    const __bf16* vbase = vt + (size_t)h * 64 * 4096;

    // ---- stage tile 0 ----
#pragma unroll
    for (int j = wave * 2; j < wave * 2 + 2; ++j) {
        gload_lds16(kb + (size_t)(kv0 + j * 8 + srow) * 512 + h * 64 + cg * 8, &Kt[0][j * 512]);
        gload_lds16(vbase + (size_t)(j * 8 + srow) * 4096 + kv0 + cg * 8,      &Vt[0][j * 512]);
    }
    __syncthreads();

    int nsteps = kv_len >> 6;
    for (int step = 0; step < nsteps; ++step) {
        int cur = step & 1;
        int kb_i = kv0 + step * 64;
        if (step < nsteps - 1) {
            int nxt = kb_i + 64;
#pragma unroll
            for (int j = wave * 2; j < wave * 2 + 2; ++j) {
                gload_lds16(kb + (size_t)(nxt + j * 8 + srow) * 512 + h * 64 + cg * 8, &Kt[cur ^ 1][j * 512]);
                gload_lds16(vbase + (size_t)(j * 8 + srow) * 4096 + nxt + cg * 8,      &Vt[cur ^ 1][j * 512]);
            }
        }
        // ---- QK^T swapped: sc[kc][r] = score[k = kb_i+kc*16+lg*4+r][q = q0+lc] ----
        const char* Kb = (const char*)&Kt[cur][0];
        f32x4 sc[4];
#pragma unroll
        for (int kc = 0; kc < 4; ++kc) {
            int row = kc * 16 + lc;
            int sw = (row & 7) << 4;
            bf16x8 kf0 = *(const bf16x8*)(Kb + ((row * 128 + lg * 16) ^ sw));
            bf16x8 kf1 = *(const bf16x8*)(Kb + ((row * 128 + 64 + lg * 16) ^ sw));
            f32x4 z = {0,0,0,0};
            z = __builtin_amdgcn_mfma_f32_16x16x32_bf16(kf0, qf0, z, 0, 0, 0);
            z = __builtin_amdgcn_mfma_f32_16x16x32_bf16(kf1, qf1, z, 0, 0, 0);
            sc[kc] = z;
        }
        // ---- p = exp2(score*0.125*log2e), masked to exact 0 by sign-extended-bit AND ----
        uint2 mw = *(const uint2*)(mrow + (kb_i >> 5));
        char* pbase = (char*)&P[wave][0];
#pragma unroll
        for (int kc = 0; kc < 4; ++kc) {
            unsigned int wsel = (kc < 2) ? mw.x : mw.y;
            bf16x4 pk;
#pragma unroll
            for (int r = 0; r < 4; ++r) {
                int bitpos = (kc & 1) * 16 + lg * 4 + r;
                float p = __builtin_amdgcn_exp2f(sc[kc][r] * S2EXP);
                int sel = ((int)(wsel << (31 - bitpos))) >> 31;   // all-ones if mask bit set
                pk[r] = (__bf16)__int_as_float(__float_as_int(p) & sel);
            }
            int byte = (lc * 128 + kc * 32 + lg * 8) ^ ((lc & 7) << 4);
            *(bf16x4*)(pbase + byte) = pk;
        }
        // ---- PV (+ l row-sum via ones-B MFMA) ----
        const char* Vb = (const char*)&Vt[cur][0];
        int swv = (lc & 7) << 4;
#pragma unroll
        for (int kk = 0; kk < 2; ++kk) {
            int pbyte = (lc * 128 + kk * 64 + lg * 16) ^ swv;
            bf16x8 pf = *(const bf16x8*)((const char*)&P[wave][0] + pbyte);
            l_acc = __builtin_amdgcn_mfma_f32_16x16x32_bf16(pf, onesf, l_acc, 0, 0, 0);
            int ch = (kk * 4 + lg) * 16;
            o0 = __builtin_amdgcn_mfma_f32_16x16x32_bf16(pf, *(const bf16x8*)(Vb + (((0 * 16 + lc) * 128 + ch) ^ swv)), o0, 0, 0, 0);
            o1 = __builtin_amdgcn_mfma_f32_16x16x32_bf16(pf, *(const bf16x8*)(Vb + (((1 * 16 + lc) * 128 + ch) ^ swv)), o1, 0, 0, 0);
            o2 = __builtin_amdgcn_mfma_f32_16x16x32_bf16(pf, *(const bf16x8*)(Vb + (((2 * 16 + lc) * 128 + ch) ^ swv)), o2, 0, 0, 0);
            o3 = __builtin_amdgcn_mfma_f32_16x16x32_bf16(pf, *(const bf16x8*)(Vb + (((3 * 16 + lc) * 128 + ch) ^ swv)), o3, 0, 0, 0);
        }
        __syncthreads();
    }
    if (opart) {
        if (lc == 0) {
#pragma unroll
            for (int r = 0; r < 4; ++r)
                stats[(size_t)sp * 32768 + (size_t)(q0 + lg * 4 + r) * 8 + h] = l_acc[r];
        }
#pragma unroll
        for (int r = 0; r < 4; ++r) {
            size_t rh = (size_t)sp * 32768 + (size_t)(q0 + lg * 4 + r) * 8 + h;
            float* dst = opart + rh * 64;
            dst[0 * 16 + lc] = o0[r];
            dst[1 * 16 + lc] = o1[r];
            dst[2 * 16 + lc] = o2[r];
            dst[3 * 16 + lc] = o3[r];
        }
    } else {
#pragma unroll
        for (int r = 0; r < 4; ++r) {
            float inv = 1.0f / l_acc[r];
            int row = q0 + lg * 4 + r;
            __bf16* dst = ao + (size_t)row * 512 + h * 64;
            dst[0 * 16 + lc] = (__bf16)(o0[r] * inv);
            dst[1 * 16 + lc] = (__bf16)(o1[r] * inv);
            dst[2 * 16 + lc] = (__bf16)(o2[r] * inv);
            dst[3 * 16 + lc] = (__bf16)(o3[r] * inv);
        }
    }
}

// ---------------- split-KV combine (2 splits, no exp needed: shared implicit max=0) ----------------
__global__ __launch_bounds__(256) void combine_kernel(const float* __restrict__ opart,
                                                      const float* __restrict__ stats,
                                                      __bf16* __restrict__ ao) {
    int t = threadIdx.x, lane = t & 63, w = t >> 6;
    int rh = blockIdx.x * 4 + w;     // row*8 + h
    float L = stats[rh] + stats[32768 + rh];
    float acc = opart[(size_t)rh * 64 + lane] + opart[(size_t)(32768 + rh) * 64 + lane];
    int row = rh >> 3, h = rh & 7;
    ao[(size_t)row * 512 + h * 64 + lane] = (__bf16)(acc / L);
}

// ---------------- final FC: out[s][n] = sum_k ao[s][k] * Wfc[n][k] + bfc[n] ----------------
__global__ __launch_bounds__(256) void fc_kernel(const __bf16* __restrict__ ao,
                                                 const __bf16* __restrict__ Wb,
                                                 const float* __restrict__ bfc,
                                                 float* __restrict__ out) {
    int bid = blockIdx.x;
    int stile = bid >> 3, nt = bid & 7;
    int t = threadIdx.x, wave = t >> 6, lane = t & 63, lg = lane >> 4, lc = lane & 15;
    int s0 = stile * 64 + wave * 16;
    int n0 = nt * 64;
    f32x4 c0 = {0,0,0,0}, c1 = {0,0,0,0}, c2 = {0,0,0,0}, c3 = {0,0,0,0};
    for (int k0 = 0; k0 < 512; k0 += 32) {
        bf16x8 af = *(const bf16x8*)(ao + (size_t)(s0 + lc) * 512 + k0 + lg * 8);
        const __bf16* wb = Wb + k0 + lg * 8;
        c0 = __builtin_amdgcn_mfma_f32_16x16x32_bf16(af, *(const bf16x8*)(wb + (size_t)(n0 + 0 * 16 + lc) * 512), c0, 0, 0, 0);
        c1 = __builtin_amdgcn_mfma_f32_16x16x32_bf16(af, *(const bf16x8*)(wb + (size_t)(n0 + 1 * 16 + lc) * 512), c1, 0, 0, 0);
        c2 = __builtin_amdgcn_mfma_f32_16x16x32_bf16(af, *(const bf16x8*)(wb + (size_t)(n0 + 2 * 16 + lc) * 512), c2, 0, 0, 0);
        c3 = __builtin_amdgcn_mfma_f32_16x16x32_bf16(af, *(const bf16x8*)(wb + (size_t)(n0 + 3 * 16 + lc) * 512), c3, 0, 0, 0);
    }
#pragma unroll
    for (int r = 0; r < 4; ++r) {
        int row = s0 + lg * 4 + r;
        float* dst = out + (size_t)row * 512 + n0;
        dst[0 * 16 + lc] = c0[r] + bfc[n0 + 0 * 16 + lc];
        dst[1 * 16 + lc] = c1[r] + bfc[n0 + 1 * 16 + lc];
        dst[2 * 16 + lc] = c2[r] + bfc[n0 + 2 * 16 + lc];
        dst[3 * 16 + lc] = c3[r] + bfc[n0 + 3 * 16 + lc];
    }
}

extern "C" void kernel_launch(void* const* d_in, const int* in_sizes, int n_in,
                              void* d_out, int out_size, void* d_ws, size_t ws_size,
                              hipStream_t stream) {
    const float* query = (const float*)d_in[0];
    const float* key   = (const float*)d_in[1];
    const float* value = (const float*)d_in[2];
    const int*   mask  = (const int*)d_in[3];
    const float* Wq  = (const float*)d_in[4];
    const float* bq  = (const float*)d_in[5];
    const float* Wk  = (const float*)d_in[6];
    const float* bk  = (const float*)d_in[7];
    const float* Wv  = (const float*)d_in[8];
    const float* bv  = (const float*)d_in[9];
    const float* Wfc = (const float*)d_in[10];
    const float* bfc = (const float*)d_in[11];

    char* ws = (char*)d_ws;
    const size_t MB = 1024 * 1024;
    __bf16* q_bf   = (__bf16*)(ws + 0 * MB);      // 4 MB  [S*H][64]
    __bf16* k_bf   = (__bf16*)(ws + 4 * MB);      // 4 MB  [S*H][64]
    __bf16* vt     = (__bf16*)(ws + 8 * MB);      // 4 MB  [H][64][S]
    __bf16* ao     = (__bf16*)(ws + 12 * MB);     // 4 MB  [S][512]
    __bf16* wfc_bf = (__bf16*)(ws + 16 * MB);     // 0.5 MB
    unsigned int* mpack = (unsigned int*)(ws + 17 * MB);  // 2 MB [S][128]
    const size_t base = 19 * MB;
    int nsplit = (ws_size >= base + 2 * (8 * MB) + 524288) ? 2 : 1;
    float* opart = (float*)(ws + base);
    float* stats = (float*)(ws + base + (size_t)nsplit * 8 * MB);

    proj_all_kernel<<<1024, 256, 0, stream>>>(query, key, value, Wq, bq, Wk, bk, Wv, bv,
                                              q_bf, k_bf, vt);
    prep_kernel<<<2080, 256, 0, stream>>>(mask, mpack, Wfc, wfc_bf);
    if (nsplit > 1) {
        attn_kernel<<<512 * nsplit, 256, 0, stream>>>(q_bf, k_bf, vt, mpack,
                                                      S_LEN / nsplit, opart, stats, ao);
        combine_kernel<<<8192, 256, 0, stream>>>(opart, stats, ao);
    } else {
        attn_kernel<<<512, 256, 0, stream>>>(q_bf, k_bf, vt, mpack,
                                             S_LEN, nullptr, nullptr, ao);
    }
    fc_kernel<<<512, 256, 0, stream>>>(ao, wfc_bf, bfc, (float*)d_out);
}